// Round 1
// baseline (424.497 us; speedup 1.0000x reference)
//
#include <hip/hip_runtime.h>
#include <hip/hip_bf16.h>
#include <stdint.h>

// ---------- types ----------
typedef __attribute__((ext_vector_type(4))) float f32x4;
typedef __attribute__((ext_vector_type(4))) unsigned int u32x4;
typedef __attribute__((ext_vector_type(8))) short bf16x8;

static __device__ __forceinline__ unsigned short f2bf(float f) {
  union { float f; unsigned int u; } v; v.f = f;
  unsigned int r = v.u + 0x7fffu + ((v.u >> 16) & 1u);   // RNE
  return (unsigned short)(r >> 16);
}
static __device__ __forceinline__ unsigned int pack2(float lo, float hi) {
  return ((unsigned int)f2bf(hi) << 16) | (unsigned int)f2bf(lo);
}
static __device__ __forceinline__ float tanh_fast(float x) {
  x = fminf(9.0f, fmaxf(-9.0f, x));                       // avoid inf -> NaN
  float t = __builtin_amdgcn_exp2f(x * 2.885390081777927f); // e^(2x)
  return (t - 1.0f) * __builtin_amdgcn_rcpf(t + 1.0f);
}
static __device__ __forceinline__ bf16x8 as_bf16x8(u32x4 v) {
  union { u32x4 u; bf16x8 b; } c; c.u = v; return c.b;
}

// async global -> LDS, 16B per lane (dest = wave-uniform base + lane*16)
#define GLOAD_LDS16(gp, lp)                                                   \
  __builtin_amdgcn_global_load_lds(                                           \
      (const __attribute__((address_space(1))) unsigned int*)(gp),            \
      (__attribute__((address_space(3))) unsigned int*)(lp), 16, 0, 0)

// ---------- kernel 0: tiled transpose fp32 -> bf16 ----------
// dst[C][R] = bf16(src[R][C])
__global__ void transpose_cvt_kernel(const float* __restrict__ src,
                                     unsigned short* __restrict__ dst,
                                     int R, int C) {
  __shared__ float tile[32][33];
  const int c0 = blockIdx.x * 32, r0 = blockIdx.y * 32;
  const int tx = threadIdx.x, ty = threadIdx.y;
#pragma unroll
  for (int i = 0; i < 4; ++i)
    tile[ty + i * 8][tx] = src[(size_t)(r0 + ty + i * 8) * C + c0 + tx];
  __syncthreads();
#pragma unroll
  for (int i = 0; i < 4; ++i)
    dst[(size_t)(c0 + ty + i * 8) * R + r0 + tx] = f2bf(tile[tx][ty + i * 8]);
}

// ---------- kernel 1: projections ----------
// projBuf rows 0..1023  : enc[m] @ W1[:512]          (fp32 out)
// projBuf rows 1024..1279: dec[m-1024] @ W1[512:] + b1
// C[m][n] = sum_k A[m][k] * W1T[n][koff+k]
__global__ __launch_bounds__(256) void proj_kernel(
    const float* __restrict__ enc, const float* __restrict__ dec,
    const unsigned short* __restrict__ W1T, const float* __restrict__ b1,
    float* __restrict__ projBuf) {
  __shared__ u32x4 lsA[64 * 8];   // 64x64 bf16, 16B-block XOR swizzled
  __shared__ u32x4 lsB[64 * 8];
  const int tid = threadIdx.x;
  const int lane = tid & 63, wid = tid >> 6;
  const int wr = wid >> 1, wc = wid & 1;          // 2x2 wave grid, 32x32 each
  const int m0 = blockIdx.x * 64, n0 = blockIdx.y * 64;
  const int koff = (m0 >= 1024) ? 512 : 0;
  const int l15 = lane & 15, l4 = lane >> 4;
  const int rrB = lane >> 3;
  const int sblkB = (lane & 7) ^ rrB;             // pre-swizzled source block

  f32x4 acc[2][2] = {};

  for (int kt = 0; kt < 8; ++kt) {
    const int k0 = kt * 64;
    if (kt) __syncthreads();
    // stage B: W1T rows n0..n0+63, cols koff+k0..+63 (global_load_lds, linear LDS)
#pragma unroll
    for (int i = 0; i < 2; ++i) {
      const int rbase = wid * 16 + i * 8;
      const unsigned short* g =
          W1T + (size_t)(n0 + rbase + rrB) * 1024 + koff + k0 + sblkB * 8;
      GLOAD_LDS16(g, &lsB[rbase * 8]);
    }
    // stage A: rows m0..m0+63, cvt fp32 -> bf16, swizzled ds_write_b128
    {
      const int r = tid >> 2;
      const int kk = (tid & 3) << 4;
      const int m = m0 + r;
      const float* g = (m < 1024) ? (enc + (size_t)m * 512 + k0 + kk)
                                  : (dec + (size_t)(m - 1024) * 512 + k0 + kk);
      u32x4 w0, w1;
      f32x4 v;
      v = *(const f32x4*)(g + 0);  w0[0] = pack2(v[0], v[1]); w0[1] = pack2(v[2], v[3]);
      v = *(const f32x4*)(g + 4);  w0[2] = pack2(v[0], v[1]); w0[3] = pack2(v[2], v[3]);
      v = *(const f32x4*)(g + 8);  w1[0] = pack2(v[0], v[1]); w1[1] = pack2(v[2], v[3]);
      v = *(const f32x4*)(g + 12); w1[2] = pack2(v[0], v[1]); w1[3] = pack2(v[2], v[3]);
      const int b0 = kk >> 3, rs = r & 7;
      lsA[r * 8 + (b0 ^ rs)] = w0;
      lsA[r * 8 + ((b0 + 1) ^ rs)] = w1;
    }
    __syncthreads();
#pragma unroll
    for (int kf = 0; kf < 2; ++kf) {
      bf16x8 a[2], b[2];
#pragma unroll
      for (int mf = 0; mf < 2; ++mf) {
        const int row = wr * 32 + mf * 16 + l15;
        a[mf] = as_bf16x8(lsA[row * 8 + (((kf << 2) + l4) ^ (row & 7))]);
      }
#pragma unroll
      for (int nf = 0; nf < 2; ++nf) {
        const int row = wc * 32 + nf * 16 + l15;
        b[nf] = as_bf16x8(lsB[row * 8 + (((kf << 2) + l4) ^ (row & 7))]);
      }
#pragma unroll
      for (int mf = 0; mf < 2; ++mf)
#pragma unroll
        for (int nf = 0; nf < 2; ++nf)
          acc[mf][nf] = __builtin_amdgcn_mfma_f32_16x16x32_bf16(
              a[mf], b[nf], acc[mf][nf], 0, 0, 0);
    }
  }
  // epilogue: C/D layout col=lane&15, row=(lane>>4)*4+j
#pragma unroll
  for (int mf = 0; mf < 2; ++mf) {
    const int row0 = m0 + wr * 32 + mf * 16 + l4 * 4;
#pragma unroll
    for (int nf = 0; nf < 2; ++nf) {
      const int col = n0 + wc * 32 + nf * 16 + l15;
      const float bias = (m0 >= 1024) ? b1[col] : 0.0f;
#pragma unroll
      for (int j = 0; j < 4; ++j)
        projBuf[(size_t)(row0 + j) * 512 + col] = acc[mf][nf][j] + bias;
    }
  }
}

// ---------- kernel 2: fused hidden + GEMM ----------
// out[m][v] = sum_h tanh(encP[m>>6][h] + decP[(m>>14)*64 + (m&63)][h]) * W2T[v][h]
// BM=128, BN=256, BK=64; 8 waves (2x4), each 64x64 output.
__global__ __launch_bounds__(512, 2) void joint_kernel(
    const float* __restrict__ projBuf, const unsigned short* __restrict__ W2T,
    float* __restrict__ out) {
  __shared__ u32x4 lsA[128 * 8];   // hidden tile 128x64 bf16, swizzled (16KB)
  __shared__ u32x4 lsB[256 * 8];   // W2T tile 256x64 bf16, swizzled  (32KB)
  const int tid = threadIdx.x;
  const int lane = tid & 63, wid = tid >> 6;
  const int wr = wid >> 2, wc = wid & 3;
  const int m0 = blockIdx.x * 128;
  const int n0 = blockIdx.y * 256;
  const int e0 = m0 >> 6;                          // encP row base (2 rows used)
  const int dbase = 1024 + ((m0 >> 14) << 6);      // decP row base in projBuf
  const int l15 = lane & 15, l4 = lane >> 4;

  f32x4 acc[4][4] = {};

  // A-staging thread mapping: 512 threads x 16 elems = 128x64
  const int r = tid >> 2;
  const int kk = (tid & 3) << 4;
  const float* geBase = projBuf + ((size_t)(e0 + (r >> 6)) << 9) + kk;
  const float* gdBase = projBuf + ((size_t)(dbase + (r & 63)) << 9) + kk;
  const int b0 = kk >> 3, rs = r & 7;
  // B-staging: pre-swizzled source block
  const int rrB = lane >> 3;
  const int sblkB = (lane & 7) ^ rrB;

  for (int kt = 0; kt < 8; ++kt) {
    const int k0 = kt * 64;
    if (kt) __syncthreads();
    // stage B first (async loads in flight under the A tanh compute)
#pragma unroll
    for (int i = 0; i < 4; ++i) {
      const int rbase = wid * 32 + i * 8;
      const unsigned short* g =
          W2T + (size_t)(n0 + rbase + rrB) * 512 + k0 + sblkB * 8;
      GLOAD_LDS16(g, &lsB[rbase * 8]);
    }
    // stage A: hidden = tanh(encP + decP), fp32 -> bf16, swizzled ds_write
    {
      const float* ge = geBase + k0;
      const float* gd = gdBase + k0;
      u32x4 w0, w1;
      f32x4 e, d;
      e = *(const f32x4*)(ge + 0);  d = *(const f32x4*)(gd + 0);
      w0[0] = pack2(tanh_fast(e[0] + d[0]), tanh_fast(e[1] + d[1]));
      w0[1] = pack2(tanh_fast(e[2] + d[2]), tanh_fast(e[3] + d[3]));
      e = *(const f32x4*)(ge + 4);  d = *(const f32x4*)(gd + 4);
      w0[2] = pack2(tanh_fast(e[0] + d[0]), tanh_fast(e[1] + d[1]));
      w0[3] = pack2(tanh_fast(e[2] + d[2]), tanh_fast(e[3] + d[3]));
      e = *(const f32x4*)(ge + 8);  d = *(const f32x4*)(gd + 8);
      w1[0] = pack2(tanh_fast(e[0] + d[0]), tanh_fast(e[1] + d[1]));
      w1[1] = pack2(tanh_fast(e[2] + d[2]), tanh_fast(e[3] + d[3]));
      e = *(const f32x4*)(ge + 12); d = *(const f32x4*)(gd + 12);
      w1[2] = pack2(tanh_fast(e[0] + d[0]), tanh_fast(e[1] + d[1]));
      w1[3] = pack2(tanh_fast(e[2] + d[2]), tanh_fast(e[3] + d[3]));
      lsA[r * 8 + (b0 ^ rs)] = w0;
      lsA[r * 8 + ((b0 + 1) ^ rs)] = w1;
    }
    __syncthreads();   // drains vmcnt (global_load_lds) + lgkmcnt (ds_write)
#pragma unroll
    for (int kf = 0; kf < 2; ++kf) {
      bf16x8 a[4], b[4];
#pragma unroll
      for (int mf = 0; mf < 4; ++mf) {
        const int row = wr * 64 + mf * 16 + l15;
        a[mf] = as_bf16x8(lsA[row * 8 + (((kf << 2) + l4) ^ (l15 & 7))]);
      }
#pragma unroll
      for (int nf = 0; nf < 4; ++nf) {
        const int row = wc * 64 + nf * 16 + l15;
        b[nf] = as_bf16x8(lsB[row * 8 + (((kf << 2) + l4) ^ (l15 & 7))]);
      }
#pragma unroll
      for (int mf = 0; mf < 4; ++mf)
#pragma unroll
        for (int nf = 0; nf < 4; ++nf)
          acc[mf][nf] = __builtin_amdgcn_mfma_f32_16x16x32_bf16(
              a[mf], b[nf], acc[mf][nf], 0, 0, 0);
    }
  }
  // epilogue
#pragma unroll
  for (int mf = 0; mf < 4; ++mf) {
    const size_t row0 = (size_t)(m0 + wr * 64 + mf * 16 + l4 * 4);
#pragma unroll
    for (int nf = 0; nf < 4; ++nf) {
      const int col = n0 + wc * 64 + nf * 16 + l15;
#pragma unroll
      for (int j = 0; j < 4; ++j)
        out[(row0 + j) * 1024 + col] = acc[mf][nf][j];
    }
  }
}

// ---------- launch ----------
extern "C" void kernel_launch(void* const* d_in, const int* in_sizes, int n_in,
                              void* d_out, int out_size, void* d_ws, size_t ws_size,
                              hipStream_t stream) {
  const float* enc = (const float*)d_in[0];   // (4,256,512)
  const float* dec = (const float*)d_in[1];   // (4,64,512)
  const float* W1  = (const float*)d_in[2];   // (1024,512)
  const float* b1  = (const float*)d_in[3];   // (512)
  const float* W2  = (const float*)d_in[4];   // (512,1024)
  float* out = (float*)d_out;                 // (4,256,64,1024)

  char* ws = (char*)d_ws;
  unsigned short* W1T = (unsigned short*)ws;               // [512][1024] bf16, 1MB
  unsigned short* W2T = (unsigned short*)(ws + (1 << 20)); // [1024][512] bf16, 1MB
  float* projBuf = (float*)(ws + (2 << 20));               // [1280][512] fp32, 2.5MB

  // W1 (1024x512) -> W1T (512x1024)
  transpose_cvt_kernel<<<dim3(512 / 32, 1024 / 32), dim3(32, 8), 0, stream>>>(
      W1, W1T, 1024, 512);
  // W2 (512x1024) -> W2T (1024x512)
  transpose_cvt_kernel<<<dim3(1024 / 32, 512 / 32), dim3(32, 8), 0, stream>>>(
      W2, W2T, 512, 1024);
  // projections (M=1280, N=512, K=512)
  proj_kernel<<<dim3(20, 8), 256, 0, stream>>>(enc, dec, W1T, b1, projBuf);
  // main fused GEMM (M=65536, N=1024, K=512)
  joint_kernel<<<dim3(512, 4), 512, 0, stream>>>(projBuf, W2T, out);
}

// Round 3
// 382.567 us; speedup vs baseline: 1.1096x; 1.1096x over previous
//
#include <hip/hip_runtime.h>
#include <hip/hip_bf16.h>
#include <stdint.h>

// ---------- types ----------
typedef __attribute__((ext_vector_type(4))) float f32x4;
typedef __attribute__((ext_vector_type(4))) unsigned int u32x4;
typedef __attribute__((ext_vector_type(8))) short bf16x8;

static __device__ __forceinline__ unsigned short f2bf(float f) {
  union { float f; unsigned int u; } v; v.f = f;
  unsigned int r = v.u + 0x7fffu + ((v.u >> 16) & 1u);   // RNE
  return (unsigned short)(r >> 16);
}
static __device__ __forceinline__ unsigned int pack2(float lo, float hi) {
  return ((unsigned int)f2bf(hi) << 16) | (unsigned int)f2bf(lo);
}
static __device__ __forceinline__ float tanh_fast(float x) {
  x = fminf(9.0f, fmaxf(-9.0f, x));                       // avoid inf -> NaN
  float t = __builtin_amdgcn_exp2f(x * 2.885390081777927f); // e^(2x)
  return (t - 1.0f) * __builtin_amdgcn_rcpf(t + 1.0f);
}
static __device__ __forceinline__ bf16x8 as_bf16x8(u32x4 v) {
  union { u32x4 u; bf16x8 b; } c; c.u = v; return c.b;
}

// async global -> LDS, 16B per lane (dest = wave-uniform base + lane*16)
#define GLOAD_LDS16(gp, lp)                                                   \
  __builtin_amdgcn_global_load_lds(                                           \
      (const __attribute__((address_space(1))) unsigned int*)(gp),            \
      (__attribute__((address_space(3))) unsigned int*)(lp), 16, 0, 0)

// ---------- kernel 0: tiled transpose fp32 -> bf16 ----------
// dst[C][R] = bf16(src[R][C])
__global__ void transpose_cvt_kernel(const float* __restrict__ src,
                                     unsigned short* __restrict__ dst,
                                     int R, int C) {
  __shared__ float tile[32][33];
  const int c0 = blockIdx.x * 32, r0 = blockIdx.y * 32;
  const int tx = threadIdx.x, ty = threadIdx.y;
#pragma unroll
  for (int i = 0; i < 4; ++i)
    tile[ty + i * 8][tx] = src[(size_t)(r0 + ty + i * 8) * C + c0 + tx];
  __syncthreads();
#pragma unroll
  for (int i = 0; i < 4; ++i)
    dst[(size_t)(c0 + ty + i * 8) * R + r0 + tx] = f2bf(tile[tx][ty + i * 8]);
}

// ---------- kernel 1: projections ----------
// projBuf rows 0..1023  : enc[m] @ W1[:512]          (fp32 out)
// projBuf rows 1024..1279: dec[m-1024] @ W1[512:] + b1
__global__ __launch_bounds__(256) void proj_kernel(
    const float* __restrict__ enc, const float* __restrict__ dec,
    const unsigned short* __restrict__ W1T, const float* __restrict__ b1,
    float* __restrict__ projBuf) {
  __shared__ u32x4 lsA[64 * 8];   // 64x64 bf16, 16B-block XOR swizzled
  __shared__ u32x4 lsB[64 * 8];
  const int tid = threadIdx.x;
  const int lane = tid & 63, wid = tid >> 6;
  const int wr = wid >> 1, wc = wid & 1;          // 2x2 wave grid, 32x32 each
  const int m0 = blockIdx.x * 64, n0 = blockIdx.y * 64;
  const int koff = (m0 >= 1024) ? 512 : 0;
  const int l15 = lane & 15, l4 = lane >> 4;
  const int rrB = lane >> 3;
  const int sblkB = (lane & 7) ^ rrB;             // pre-swizzled source block

  f32x4 acc[2][2] = {};

  for (int kt = 0; kt < 8; ++kt) {
    const int k0 = kt * 64;
    if (kt) __syncthreads();
#pragma unroll
    for (int i = 0; i < 2; ++i) {
      const int rbase = wid * 16 + i * 8;
      const unsigned short* g =
          W1T + (size_t)(n0 + rbase + rrB) * 1024 + koff + k0 + sblkB * 8;
      GLOAD_LDS16(g, &lsB[rbase * 8]);
    }
    {
      const int r = tid >> 2;
      const int kk = (tid & 3) << 4;
      const int m = m0 + r;
      const float* g = (m < 1024) ? (enc + (size_t)m * 512 + k0 + kk)
                                  : (dec + (size_t)(m - 1024) * 512 + k0 + kk);
      u32x4 w0, w1;
      f32x4 v;
      v = *(const f32x4*)(g + 0);  w0[0] = pack2(v[0], v[1]); w0[1] = pack2(v[2], v[3]);
      v = *(const f32x4*)(g + 4);  w0[2] = pack2(v[0], v[1]); w0[3] = pack2(v[2], v[3]);
      v = *(const f32x4*)(g + 8);  w1[0] = pack2(v[0], v[1]); w1[1] = pack2(v[2], v[3]);
      v = *(const f32x4*)(g + 12); w1[2] = pack2(v[0], v[1]); w1[3] = pack2(v[2], v[3]);
      const int b0 = kk >> 3, rs = r & 7;
      lsA[r * 8 + (b0 ^ rs)] = w0;
      lsA[r * 8 + ((b0 + 1) ^ rs)] = w1;
    }
    __syncthreads();
#pragma unroll
    for (int kf = 0; kf < 2; ++kf) {
      bf16x8 a[2], b[2];
#pragma unroll
      for (int mf = 0; mf < 2; ++mf) {
        const int row = wr * 32 + mf * 16 + l15;
        a[mf] = as_bf16x8(lsA[row * 8 + (((kf << 2) + l4) ^ (row & 7))]);
      }
#pragma unroll
      for (int nf = 0; nf < 2; ++nf) {
        const int row = wc * 32 + nf * 16 + l15;
        b[nf] = as_bf16x8(lsB[row * 8 + (((kf << 2) + l4) ^ (row & 7))]);
      }
#pragma unroll
      for (int mf = 0; mf < 2; ++mf)
#pragma unroll
        for (int nf = 0; nf < 2; ++nf)
          acc[mf][nf] = __builtin_amdgcn_mfma_f32_16x16x32_bf16(
              a[mf], b[nf], acc[mf][nf], 0, 0, 0);
    }
  }
#pragma unroll
  for (int mf = 0; mf < 2; ++mf) {
    const int row0 = m0 + wr * 32 + mf * 16 + l4 * 4;
#pragma unroll
    for (int nf = 0; nf < 2; ++nf) {
      const int col = n0 + wc * 32 + nf * 16 + l15;
      const float bias = (m0 >= 1024) ? b1[col] : 0.0f;
#pragma unroll
      for (int j = 0; j < 4; ++j)
        projBuf[(size_t)(row0 + j) * 512 + col] = acc[mf][nf][j] + bias;
    }
  }
}

// ---------- kernel 2: hidden = tanh(encP + decP) -> bf16 [65536][512] ----------
// row m: encP row = m>>6, decP row = 1024 + (m>>14)*64 + (m&63)
__global__ __launch_bounds__(256) void hidden_kernel(
    const float* __restrict__ projBuf, unsigned short* __restrict__ hid) {
  const int tid = threadIdx.x;
  const int m = blockIdx.x * 8 + (tid >> 5);
  const int h0 = (tid & 31) * 16;
  const float* ge = projBuf + ((size_t)(m >> 6) << 9) + h0;
  const float* gd =
      projBuf + ((size_t)(1024 + ((m >> 14) << 6) + (m & 63)) << 9) + h0;
  u32x4 w0, w1;
  f32x4 e, d;
  e = *(const f32x4*)(ge + 0);  d = *(const f32x4*)(gd + 0);
  w0[0] = pack2(tanh_fast(e[0] + d[0]), tanh_fast(e[1] + d[1]));
  w0[1] = pack2(tanh_fast(e[2] + d[2]), tanh_fast(e[3] + d[3]));
  e = *(const f32x4*)(ge + 4);  d = *(const f32x4*)(gd + 4);
  w0[2] = pack2(tanh_fast(e[0] + d[0]), tanh_fast(e[1] + d[1]));
  w0[3] = pack2(tanh_fast(e[2] + d[2]), tanh_fast(e[3] + d[3]));
  e = *(const f32x4*)(ge + 8);  d = *(const f32x4*)(gd + 8);
  w1[0] = pack2(tanh_fast(e[0] + d[0]), tanh_fast(e[1] + d[1]));
  w1[1] = pack2(tanh_fast(e[2] + d[2]), tanh_fast(e[3] + d[3]));
  e = *(const f32x4*)(ge + 12); d = *(const f32x4*)(gd + 12);
  w1[2] = pack2(tanh_fast(e[0] + d[0]), tanh_fast(e[1] + d[1]));
  w1[3] = pack2(tanh_fast(e[2] + d[2]), tanh_fast(e[3] + d[3]));
  unsigned short* o = hid + ((size_t)m << 9) + h0;
  *(u32x4*)(o) = w0;
  *(u32x4*)(o + 8) = w1;
}

// ---------- kernel 3: pure bf16 GEMM (m97 structure) ----------
// out[m][v] = sum_k hid[m][k] * W2T[v][k];  M=65536 N=1024 K=512
// BM=BN=128, BK=64, 4 waves (2x2), 64x64 per wave.
__global__ __launch_bounds__(256) void gemm_kernel(
    const unsigned short* __restrict__ hid,
    const unsigned short* __restrict__ W2T, float* __restrict__ out) {
  __shared__ u32x4 lsA[128 * 8];   // 16KB, swizzled
  __shared__ u32x4 lsB[128 * 8];   // 16KB
  const int tid = threadIdx.x;
  const int lane = tid & 63, wid = tid >> 6;
  const int wr = wid >> 1, wc = wid & 1;
  // XCD-aware swizzle: nwg=4096, 8 XCDs -> 512 consecutive sids per XCD
  const int bid = blockIdx.x;
  const int sid = (bid & 7) * 512 + (bid >> 3);
  const int m0 = (sid >> 3) * 128;     // 512 m-blocks
  const int n0 = (sid & 7) * 128;      // 8 n-blocks (B reused across adjacent sids)
  const int l15 = lane & 15, l4 = lane >> 4;
  const int rr = lane >> 3;
  const int sblk = (lane & 7) ^ rr;    // pre-swizzled source 16B-block

  f32x4 acc[4][4] = {};
  const unsigned short* gA = hid + (size_t)(m0 + rr) * 512 + sblk * 8;
  const unsigned short* gB = W2T + (size_t)(n0 + rr) * 512 + sblk * 8;

  for (int kt = 0; kt < 8; ++kt) {
    const int k0 = kt * 64;
    if (kt) __syncthreads();
#pragma unroll
    for (int i = 0; i < 4; ++i) {
      const int rbase = wid * 32 + i * 8;
      GLOAD_LDS16(gA + (size_t)rbase * 512 + k0, &lsA[rbase * 8]);
      GLOAD_LDS16(gB + (size_t)rbase * 512 + k0, &lsB[rbase * 8]);
    }
    __syncthreads();   // compiler emits vmcnt(0) drain here
#pragma unroll
    for (int kf = 0; kf < 2; ++kf) {
      bf16x8 a[4], b[4];
#pragma unroll
      for (int mf = 0; mf < 4; ++mf) {
        const int row = wr * 64 + mf * 16 + l15;
        a[mf] = as_bf16x8(lsA[row * 8 + (((kf << 2) + l4) ^ (row & 7))]);
      }
#pragma unroll
      for (int nf = 0; nf < 4; ++nf) {
        const int row = wc * 64 + nf * 16 + l15;
        b[nf] = as_bf16x8(lsB[row * 8 + (((kf << 2) + l4) ^ (row & 7))]);
      }
#pragma unroll
      for (int mf = 0; mf < 4; ++mf)
#pragma unroll
        for (int nf = 0; nf < 4; ++nf)
          acc[mf][nf] = __builtin_amdgcn_mfma_f32_16x16x32_bf16(
              a[mf], b[nf], acc[mf][nf], 0, 0, 0);
    }
  }
#pragma unroll
  for (int mf = 0; mf < 4; ++mf) {
    const size_t row0 = (size_t)(m0 + wr * 64 + mf * 16 + l4 * 4);
#pragma unroll
    for (int nf = 0; nf < 4; ++nf) {
      const int col = n0 + wc * 64 + nf * 16 + l15;
#pragma unroll
      for (int j = 0; j < 4; ++j)
        out[(row0 + j) * 1024 + col] = acc[mf][nf][j];
    }
  }
}

// ---------- fallback (R1 fused joint kernel, used if ws too small) ----------
__global__ __launch_bounds__(512, 2) void joint_kernel(
    const float* __restrict__ projBuf, const unsigned short* __restrict__ W2T,
    float* __restrict__ out) {
  __shared__ u32x4 lsA[128 * 8];
  __shared__ u32x4 lsB[256 * 8];
  const int tid = threadIdx.x;
  const int lane = tid & 63, wid = tid >> 6;
  const int wr = wid >> 2, wc = wid & 3;
  const int m0 = blockIdx.x * 128;
  const int n0 = blockIdx.y * 256;
  const int e0 = m0 >> 6;
  const int dbase = 1024 + ((m0 >> 14) << 6);
  const int l15 = lane & 15, l4 = lane >> 4;

  f32x4 acc[4][4] = {};

  const int r = tid >> 2;
  const int kk = (tid & 3) << 4;
  const float* geBase = projBuf + ((size_t)(e0 + (r >> 6)) << 9) + kk;
  const float* gdBase = projBuf + ((size_t)(dbase + (r & 63)) << 9) + kk;
  const int b0 = kk >> 3, rs = r & 7;
  const int rrB = lane >> 3;
  const int sblkB = (lane & 7) ^ rrB;

  for (int kt = 0; kt < 8; ++kt) {
    const int k0 = kt * 64;
    if (kt) __syncthreads();
#pragma unroll
    for (int i = 0; i < 4; ++i) {
      const int rbase = wid * 32 + i * 8;
      const unsigned short* g =
          W2T + (size_t)(n0 + rbase + rrB) * 512 + k0 + sblkB * 8;
      GLOAD_LDS16(g, &lsB[rbase * 8]);
    }
    {
      const float* ge = geBase + k0;
      const float* gd = gdBase + k0;
      u32x4 w0, w1;
      f32x4 e, d;
      e = *(const f32x4*)(ge + 0);  d = *(const f32x4*)(gd + 0);
      w0[0] = pack2(tanh_fast(e[0] + d[0]), tanh_fast(e[1] + d[1]));
      w0[1] = pack2(tanh_fast(e[2] + d[2]), tanh_fast(e[3] + d[3]));
      e = *(const f32x4*)(ge + 4);  d = *(const f32x4*)(gd + 4);
      w0[2] = pack2(tanh_fast(e[0] + d[0]), tanh_fast(e[1] + d[1]));
      w0[3] = pack2(tanh_fast(e[2] + d[2]), tanh_fast(e[3] + d[3]));
      e = *(const f32x4*)(ge + 8);  d = *(const f32x4*)(gd + 8);
      w1[0] = pack2(tanh_fast(e[0] + d[0]), tanh_fast(e[1] + d[1]));
      w1[1] = pack2(tanh_fast(e[2] + d[2]), tanh_fast(e[3] + d[3]));
      e = *(const f32x4*)(ge + 12); d = *(const f32x4*)(gd + 12);
      w1[2] = pack2(tanh_fast(e[0] + d[0]), tanh_fast(e[1] + d[1]));
      w1[3] = pack2(tanh_fast(e[2] + d[2]), tanh_fast(e[3] + d[3]));
      lsA[r * 8 + (b0 ^ rs)] = w0;
      lsA[r * 8 + ((b0 + 1) ^ rs)] = w1;
    }
    __syncthreads();
#pragma unroll
    for (int kf = 0; kf < 2; ++kf) {
      bf16x8 a[4], b[4];
#pragma unroll
      for (int mf = 0; mf < 4; ++mf) {
        const int row = wr * 64 + mf * 16 + l15;
        a[mf] = as_bf16x8(lsA[row * 8 + (((kf << 2) + l4) ^ (l15 & 7))]);
      }
#pragma unroll
      for (int nf = 0; nf < 4; ++nf) {
        const int row = wc * 64 + nf * 16 + l15;
        b[nf] = as_bf16x8(lsB[row * 8 + (((kf << 2) + l4) ^ (l15 & 7))]);
      }
#pragma unroll
      for (int mf = 0; mf < 4; ++mf)
#pragma unroll
        for (int nf = 0; nf < 4; ++nf)
          acc[mf][nf] = __builtin_amdgcn_mfma_f32_16x16x32_bf16(
              a[mf], b[nf], acc[mf][nf], 0, 0, 0);
    }
  }
#pragma unroll
  for (int mf = 0; mf < 4; ++mf) {
    const size_t row0 = (size_t)(m0 + wr * 64 + mf * 16 + l4 * 4);
#pragma unroll
    for (int nf = 0; nf < 4; ++nf) {
      const int col = n0 + wc * 64 + nf * 16 + l15;
#pragma unroll
      for (int j = 0; j < 4; ++j)
        out[(row0 + j) * 1024 + col] = acc[mf][nf][j];
    }
  }
}

// ---------- launch ----------
extern "C" void kernel_launch(void* const* d_in, const int* in_sizes, int n_in,
                              void* d_out, int out_size, void* d_ws, size_t ws_size,
                              hipStream_t stream) {
  const float* enc = (const float*)d_in[0];   // (4,256,512)
  const float* dec = (const float*)d_in[1];   // (4,64,512)
  const float* W1  = (const float*)d_in[2];   // (1024,512)
  const float* b1  = (const float*)d_in[3];   // (512)
  const float* W2  = (const float*)d_in[4];   // (512,1024)
  float* out = (float*)d_out;                 // (4,256,64,1024)

  char* ws = (char*)d_ws;
  unsigned short* W1T = (unsigned short*)ws;                        // 1 MB
  unsigned short* W2T = (unsigned short*)(ws + (1 << 20));          // 1 MB
  float* projBuf = (float*)(ws + (2 << 20));                        // 2.5 MB
  unsigned short* hid = (unsigned short*)(ws + (5u << 20));         // 64 MB
  const size_t need = (5u << 20) + (64u << 20);

  transpose_cvt_kernel<<<dim3(16, 32), dim3(32, 8), 0, stream>>>(W1, W1T, 1024, 512);
  transpose_cvt_kernel<<<dim3(32, 16), dim3(32, 8), 0, stream>>>(W2, W2T, 512, 1024);
  proj_kernel<<<dim3(20, 8), 256, 0, stream>>>(enc, dec, W1T, b1, projBuf);

  if (ws_size >= need) {
    hidden_kernel<<<8192, 256, 0, stream>>>(projBuf, hid);
    gemm_kernel<<<4096, 256, 0, stream>>>(hid, W2T, out);
  } else {
    joint_kernel<<<dim3(512, 4), 512, 0, stream>>>(projBuf, W2T, out);
  }
}